// Round 6
// baseline (153.162 us; speedup 1.0000x reference)
//
#include <hip/hip_runtime.h>
#include <math.h>

// fp16-MFMA flash attention (no-max softmax), S=8192, D=128, fp32 in/out.
// R6: 16 k-slices (512 keys), grid 1024, launch_bounds(256,3) -> 3 waves/SIMD
// (R5 was grid-capped at 2). Else identical to R5: transposed-S fp16 QK^T,
// in-register P transpose via shfl_xor(32), async dbuf staging, 1 barrier/iter.

typedef _Float16 f16x8 __attribute__((ext_vector_type(8)));
typedef float    f32x16 __attribute__((ext_vector_type(16)));

constexpr int S_LEN = 8192;
constexpr int D_K   = 128;
constexpr int NKT   = 256;   // 32-key tiles
constexpr int NSLICE = 16;   // 512-key slices
constexpr int ITERS  = (S_LEN / NSLICE) / 32;   // 16 tiles per slice

// ws: l[8192] fp32 | per-tile frags: [K 512 uint4 | V 512 uint4] x 256 tiles
constexpr size_t WS_L_OFF = 0;
constexpr size_t KV_OFF   = 32768;

#define CSCALE (0.08838834764831845f * 1.44269504088896340736f)

union UH8 { _Float16 h[8]; uint4 q; f16x8 v; };
union UF4 { unsigned u[4]; uint4 q; f16x8 v; };

__device__ inline void async16(const uint4* g, uint4* l) {
  __builtin_amdgcn_global_load_lds(
      (const __attribute__((address_space(1))) unsigned int*)g,
      (__attribute__((address_space(3))) unsigned int*)l, 16, 0, 0);
}

// ---------------- prep: global->global frag build + zero out/ws_l ----------
__global__ __launch_bounds__(512) void attn_prep(const float* __restrict__ K,
                                                 const float* __restrict__ V,
                                                 float* __restrict__ out,
                                                 char* __restrict__ ws) {
  const int t = blockIdx.x * 512 + threadIdx.x;
  uint4* KVg = (uint4*)(ws + KV_OFF);
  if (t < 131072) {
    // K frag: lane holds K[key=lane&31][d0..d0+7], d0 = s*16 + (lane>>5)*8
    int kt = t >> 9, idx = t & 511;
    int lane = idx & 63, s = idx >> 6;
    int key = kt * 32 + (lane & 31);
    int d0  = s * 16 + (lane >> 5) * 8;
    const float4* src = (const float4*)(K + (size_t)key * D_K + d0);
    float4 a = src[0], b = src[1];
    float f[8] = {a.x, a.y, a.z, a.w, b.x, b.y, b.z, b.w};
    UH8 h;
    #pragma unroll
    for (int j = 0; j < 8; ++j) h.h[j] = (_Float16)f[j];
    KVg[(size_t)kt * 1024 + idx] = h.q;
  } else if (t < 262144) {
    // V frag: lane holds V[kb..kb+7][d], d = c*32 + (lane&31)
    int g = t - 131072;
    int kt = g >> 9, idx = g & 511;
    int lane = idx & 63, c = (idx >> 6) & 3, kstep = idx >> 8;
    int d  = c * 32 + (lane & 31);
    int kb = kt * 32 + kstep * 16 + (lane >> 5) * 8;
    UH8 h;
    #pragma unroll
    for (int j = 0; j < 8; ++j) h.h[j] = (_Float16)V[(size_t)(kb + j) * D_K + d];
    KVg[(size_t)kt * 1024 + 512 + idx] = h.q;
  } else if (t < 327680) {
    int i = t - 262144;  // zero out: 65536 threads x 4 float4
    float4 z = make_float4(0.f, 0.f, 0.f, 0.f);
    float4* o4 = (float4*)out;
    #pragma unroll
    for (int j = 0; j < 4; ++j) o4[(size_t)i * 4 + j] = z;
  } else if (t < 329728) {
    int i = t - 327680;  // zero ws_l: 2048 float4
    ((float4*)(ws + WS_L_OFF))[i] = make_float4(0.f, 0.f, 0.f, 0.f);
  }
}

// ---------------- main attention kernel ----------------
__global__ __launch_bounds__(256, 3)
void attn_main(const float* __restrict__ Qg, float* __restrict__ out,
               char* __restrict__ ws) {
  __shared__ uint4 KV[2][1024];   // dbuf: [K 512 | V 512]

  const int tid   = threadIdx.x;
  const int wave  = tid >> 6;
  const int lane  = tid & 63;
  const int lrow  = lane & 31;
  const int lhalf = lane >> 5;

  const int blk = blockIdx.x;
  const int ks  = blk & 15;              // k-slice; XCD = ks&7 (blocks 16 apart)
  const int qb  = blk >> 4;              // 0..63
  const int qw  = qb * 128 + wave * 32;  // wave's 32-row q base

  float* ws_l = (float*)(ws + WS_L_OFF);

  // ---- Q B-frags: lane holds Q[q=lane&31][d=(lane>>5)*8+j + 16s], scaled ----
  f16x8 qf[8];
  {
    const int q = qw + lrow;
    #pragma unroll
    for (int s = 0; s < 8; ++s) {
      const float4* src = (const float4*)(Qg + (size_t)q * D_K + s * 16 + lhalf * 8);
      float4 a = src[0], b = src[1];
      float f[8] = {a.x, a.y, a.z, a.w, b.x, b.y, b.z, b.w};
      UH8 h;
      #pragma unroll
      for (int j = 0; j < 8; ++j) h.h[j] = (_Float16)(f[j] * CSCALE);
      qf[s] = h.v;
    }
  }

  f32x16 O0{}, O1{}, O2{}, O3{};
  float lsum = 0.f;

  const uint4* KVg = (const uint4*)(ws + KV_OFF);

  // prologue: stage tile 0
  {
    const size_t base = (size_t)(ks * ITERS) * 1024;
    #pragma unroll
    for (int i = 0; i < 4; ++i)
      async16(KVg + base + i * 256 + tid, &KV[0][i * 256 + tid]);
  }

  for (int it = 0; it < ITERS; ++it) {
    const int buf = it & 1;
    __syncthreads();   // drains async loads -> KV[buf] ready

    if (it + 1 < ITERS) {
      const size_t base = (size_t)(ks * ITERS + it + 1) * 1024;
      #pragma unroll
      for (int i = 0; i < 4; ++i)
        async16(KVg + base + i * 256 + tid, &KV[buf ^ 1][i * 256 + tid]);
    }

    // ---- S^T = K Q^T : A=K-frag, B=Q-frag -> q on lane&31, keys on regs ----
    f32x16 S{};
    #pragma unroll
    for (int s = 0; s < 8; ++s) {
      f16x8 kf = __builtin_bit_cast(f16x8, KV[buf][s * 64 + lane]);
      S = __builtin_amdgcn_mfma_f32_32x32x16_f16(kf, qf[s], S, 0, 0, 0);
    }

    // ---- P^T = exp2(S^T); per-lane row sums; pack to fp16 pairs ----
    unsigned pk[8];
    #pragma unroll
    for (int i = 0; i < 8; ++i) {
      float p0 = __builtin_amdgcn_exp2f(S[2 * i]);
      float p1 = __builtin_amdgcn_exp2f(S[2 * i + 1]);
      lsum += p0 + p1;
      pk[i] = __builtin_bit_cast(unsigned, __builtin_amdgcn_cvt_pkrtz(p0, p1));
    }

    // ---- in-register transpose to P A-frags (lane<->lane+32 half swap) ----
    unsigned s0 = __shfl_xor(pk[0], 32), s1 = __shfl_xor(pk[1], 32);
    unsigned s2 = __shfl_xor(pk[2], 32), s3 = __shfl_xor(pk[3], 32);
    unsigned s4 = __shfl_xor(pk[4], 32), s5 = __shfl_xor(pk[5], 32);
    unsigned s6 = __shfl_xor(pk[6], 32), s7 = __shfl_xor(pk[7], 32);
    UF4 A0, A1;
    A0.u[0] = lhalf ? s2 : pk[0];
    A0.u[1] = lhalf ? s3 : pk[1];
    A0.u[2] = lhalf ? pk[2] : s0;
    A0.u[3] = lhalf ? pk[3] : s1;
    A1.u[0] = lhalf ? s6 : pk[4];
    A1.u[1] = lhalf ? s7 : pk[5];
    A1.u[2] = lhalf ? pk[6] : s4;
    A1.u[3] = lhalf ? pk[7] : s5;

    // ---- O += P V : 8 MFMAs ----
    #pragma unroll
    for (int kstep = 0; kstep < 2; ++kstep) {
      f16x8 pf = kstep ? A1.v : A0.v;
      f16x8 v0 = __builtin_bit_cast(f16x8, KV[buf][512 + kstep * 256 +   0 + lane]);
      f16x8 v1 = __builtin_bit_cast(f16x8, KV[buf][512 + kstep * 256 +  64 + lane]);
      f16x8 v2 = __builtin_bit_cast(f16x8, KV[buf][512 + kstep * 256 + 128 + lane]);
      f16x8 v3 = __builtin_bit_cast(f16x8, KV[buf][512 + kstep * 256 + 192 + lane]);
      O0 = __builtin_amdgcn_mfma_f32_32x32x16_f16(pf, v0, O0, 0, 0, 0);
      O1 = __builtin_amdgcn_mfma_f32_32x32x16_f16(pf, v1, O1, 0, 0, 0);
      O2 = __builtin_amdgcn_mfma_f32_32x32x16_f16(pf, v2, O2, 0, 0, 0);
      O3 = __builtin_amdgcn_mfma_f32_32x32x16_f16(pf, v3, O3, 0, 0, 0);
    }
  }

  // ---- epilogue ----
  lsum += __shfl_xor(lsum, 32);           // combine the two key-halves
  if (lhalf == 0) atomicAdd(ws_l + qw + lrow, lsum);  // q = lrow, coalesced

  #pragma unroll
  for (int r = 0; r < 16; ++r) {
    int row = (r & 3) + 8 * (r >> 2) + 4 * lhalf;     // q row (C-layout)
    float* dst = out + (size_t)(qw + row) * D_K + lrow;
    atomicAdd(dst +  0, O0[r]);
    atomicAdd(dst + 32, O1[r]);
    atomicAdd(dst + 64, O2[r]);
    atomicAdd(dst + 96, O3[r]);
  }
}

// ---------------- normalize ----------------
__global__ __launch_bounds__(256) void attn_norm(float* __restrict__ out,
                                                 const float* __restrict__ ws_l) {
  int i = blockIdx.x * 256 + threadIdx.x;
  float4* o4 = (float4*)out;
  float4 o = o4[i];
  float inv = 1.0f / ws_l[i >> 5];
  o.x *= inv; o.y *= inv; o.z *= inv; o.w *= inv;
  o4[i] = o;
}

extern "C" void kernel_launch(void* const* d_in, const int* in_sizes, int n_in,
                              void* d_out, int out_size, void* d_ws, size_t ws_size,
                              hipStream_t stream) {
  const float* q = (const float*)d_in[0];
  const float* k = (const float*)d_in[1];
  const float* v = (const float*)d_in[2];
  float* out = (float*)d_out;
  char* ws = (char*)d_ws;

  attn_prep<<<dim3(644), dim3(512), 0, stream>>>(k, v, out, ws);
  attn_main<<<dim3(1024), dim3(256), 0, stream>>>(q, out, ws);
  attn_norm<<<dim3(1024), dim3(256), 0, stream>>>(out, (const float*)ws);
}

// Round 7
// 114.256 us; speedup vs baseline: 1.3405x; 1.3405x over previous
//
#include <hip/hip_runtime.h>
#include <math.h>

// fp16-MFMA flash attention (no-max softmax), S=8192, D=128, fp32 in/out.
// R7: atomic epilogue replaced by per-slice partial buffers + reduce in norm
// (atomic fallback if ws too small); dual-S accumulators to halve the QK
// dependent-MFMA chain; 8 slices, grid 512, async dbuf staging (R5 base).

typedef _Float16 f16x8 __attribute__((ext_vector_type(8)));
typedef float    f32x16 __attribute__((ext_vector_type(16)));

constexpr int S_LEN = 8192;
constexpr int D_K   = 128;
constexpr int NSLICE = 8;
constexpr int ITERS  = (S_LEN / NSLICE) / 32;   // 32 tiles per 1024-key slice

// ws: Lpart[8][8192] fp32 (256 KB) | KV frags (8 MB) | Opart[7] x 4 MB
constexpr size_t WS_L_OFF  = 0;
constexpr size_t KV_OFF    = 262144;
constexpr size_t PART_OFF  = KV_OFF + (size_t)256 * 16384;          // 8650752
constexpr size_t WS_NEED   = PART_OFF + (size_t)7 * S_LEN * D_K * 4; // ~38 MB

#define CSCALE (0.08838834764831845f * 1.44269504088896340736f)

union UH8 { _Float16 h[8]; uint4 q; f16x8 v; };
union UF4 { unsigned u[4]; uint4 q; f16x8 v; };

__device__ inline void async16(const uint4* g, uint4* l) {
  __builtin_amdgcn_global_load_lds(
      (const __attribute__((address_space(1))) unsigned int*)g,
      (__attribute__((address_space(3))) unsigned int*)l, 16, 0, 0);
}

// ---------------- prep: global->global frag build (+ zero out/ws_l if atomic path) ----
template <bool ZOUT>
__global__ __launch_bounds__(512) void attn_prep(const float* __restrict__ K,
                                                 const float* __restrict__ V,
                                                 float* __restrict__ out,
                                                 char* __restrict__ ws) {
  const int t = blockIdx.x * 512 + threadIdx.x;
  uint4* KVg = (uint4*)(ws + KV_OFF);
  if (t < 131072) {
    // K frag: lane holds K[key=lane&31][d0..d0+7], d0 = s*16 + (lane>>5)*8
    int kt = t >> 9, idx = t & 511;
    int lane = idx & 63, s = idx >> 6;
    int key = kt * 32 + (lane & 31);
    int d0  = s * 16 + (lane >> 5) * 8;
    const float4* src = (const float4*)(K + (size_t)key * D_K + d0);
    float4 a = src[0], b = src[1];
    float f[8] = {a.x, a.y, a.z, a.w, b.x, b.y, b.z, b.w};
    UH8 h;
    #pragma unroll
    for (int j = 0; j < 8; ++j) h.h[j] = (_Float16)f[j];
    KVg[(size_t)kt * 1024 + idx] = h.q;
  } else if (t < 262144) {
    // V frag: lane holds V[kb..kb+7][d], d = c*32 + (lane&31)
    int g = t - 131072;
    int kt = g >> 9, idx = g & 511;
    int lane = idx & 63, c = (idx >> 6) & 3, kstep = idx >> 8;
    int d  = c * 32 + (lane & 31);
    int kb = kt * 32 + kstep * 16 + (lane >> 5) * 8;
    UH8 h;
    #pragma unroll
    for (int j = 0; j < 8; ++j) h.h[j] = (_Float16)V[(size_t)(kb + j) * D_K + d];
    KVg[(size_t)kt * 1024 + 512 + idx] = h.q;
  } else if (ZOUT && t < 327680) {
    int i = t - 262144;  // zero out: 65536 threads x 4 float4
    float4 z = make_float4(0.f, 0.f, 0.f, 0.f);
    float4* o4 = (float4*)out;
    #pragma unroll
    for (int j = 0; j < 4; ++j) o4[(size_t)i * 4 + j] = z;
  } else if (ZOUT && t < 330176) {
    int i = t - 327680;  // zero ws_l slice 0 (+ extras harmless): 2048 float4
    if (i < 2048) ((float4*)(ws + WS_L_OFF))[i] = make_float4(0.f, 0.f, 0.f, 0.f);
  }
}

// ---------------- main attention kernel ----------------
template <bool PARTIAL>
__global__ __launch_bounds__(256, 2)
void attn_main(const float* __restrict__ Qg, float* __restrict__ out,
               char* __restrict__ ws) {
  __shared__ uint4 KV[2][1024];   // dbuf: [K 512 | V 512]

  const int tid   = threadIdx.x;
  const int wave  = tid >> 6;
  const int lane  = tid & 63;
  const int lrow  = lane & 31;
  const int lhalf = lane >> 5;

  const int blk = blockIdx.x;
  const int ks  = blk & 7;               // k-slice (XCD-pinned by dispatch % 8)
  const int qb  = blk >> 3;              // 0..63
  const int qw  = qb * 128 + wave * 32;  // wave's 32-row q base

  float* ws_l = (float*)(ws + WS_L_OFF);

  // ---- Q B-frags: lane holds Q[q=lane&31][d=(lane>>5)*8+j + 16s], scaled ----
  f16x8 qf[8];
  {
    const int q = qw + lrow;
    #pragma unroll
    for (int s = 0; s < 8; ++s) {
      const float4* src = (const float4*)(Qg + (size_t)q * D_K + s * 16 + lhalf * 8);
      float4 a = src[0], b = src[1];
      float f[8] = {a.x, a.y, a.z, a.w, b.x, b.y, b.z, b.w};
      UH8 h;
      #pragma unroll
      for (int j = 0; j < 8; ++j) h.h[j] = (_Float16)(f[j] * CSCALE);
      qf[s] = h.v;
    }
  }

  f32x16 O0{}, O1{}, O2{}, O3{};
  float lsum = 0.f;

  const uint4* KVg = (const uint4*)(ws + KV_OFF);

  // prologue: stage tile 0
  {
    const size_t base = (size_t)(ks * ITERS) * 1024;
    #pragma unroll
    for (int i = 0; i < 4; ++i)
      async16(KVg + base + i * 256 + tid, &KV[0][i * 256 + tid]);
  }

  for (int it = 0; it < ITERS; ++it) {
    const int buf = it & 1;
    __syncthreads();   // drains async loads -> KV[buf] ready

    if (it + 1 < ITERS) {
      const size_t base = (size_t)(ks * ITERS + it + 1) * 1024;
      #pragma unroll
      for (int i = 0; i < 4; ++i)
        async16(KVg + base + i * 256 + tid, &KV[buf ^ 1][i * 256 + tid]);
    }

    // ---- S^T = K Q^T : dual accumulators, two interleaved 4-deep chains ----
    f32x16 Sa{}, Sb{};
    #pragma unroll
    for (int s = 0; s < 4; ++s) {
      f16x8 ka = __builtin_bit_cast(f16x8, KV[buf][(2 * s    ) * 64 + lane]);
      f16x8 kb = __builtin_bit_cast(f16x8, KV[buf][(2 * s + 1) * 64 + lane]);
      Sa = __builtin_amdgcn_mfma_f32_32x32x16_f16(ka, qf[2 * s    ], Sa, 0, 0, 0);
      Sb = __builtin_amdgcn_mfma_f32_32x32x16_f16(kb, qf[2 * s + 1], Sb, 0, 0, 0);
    }

    // ---- P^T = exp2(Sa+Sb); per-lane row sums; pack to fp16 pairs ----
    unsigned pk[8];
    #pragma unroll
    for (int i = 0; i < 8; ++i) {
      float p0 = __builtin_amdgcn_exp2f(Sa[2 * i]     + Sb[2 * i]);
      float p1 = __builtin_amdgcn_exp2f(Sa[2 * i + 1] + Sb[2 * i + 1]);
      lsum += p0 + p1;
      pk[i] = __builtin_bit_cast(unsigned, __builtin_amdgcn_cvt_pkrtz(p0, p1));
    }

    // ---- in-register transpose to P A-frags (lane<->lane+32 half swap) ----
    unsigned s0 = __shfl_xor(pk[0], 32), s1 = __shfl_xor(pk[1], 32);
    unsigned s2 = __shfl_xor(pk[2], 32), s3 = __shfl_xor(pk[3], 32);
    unsigned s4 = __shfl_xor(pk[4], 32), s5 = __shfl_xor(pk[5], 32);
    unsigned s6 = __shfl_xor(pk[6], 32), s7 = __shfl_xor(pk[7], 32);
    UF4 A0, A1;
    A0.u[0] = lhalf ? s2 : pk[0];
    A0.u[1] = lhalf ? s3 : pk[1];
    A0.u[2] = lhalf ? pk[2] : s0;
    A0.u[3] = lhalf ? pk[3] : s1;
    A1.u[0] = lhalf ? s6 : pk[4];
    A1.u[1] = lhalf ? s7 : pk[5];
    A1.u[2] = lhalf ? pk[6] : s4;
    A1.u[3] = lhalf ? pk[7] : s5;

    // ---- O += P V : 8 MFMAs, 4 independent chains ----
    #pragma unroll
    for (int kstep = 0; kstep < 2; ++kstep) {
      f16x8 pf = kstep ? A1.v : A0.v;
      f16x8 v0 = __builtin_bit_cast(f16x8, KV[buf][512 + kstep * 256 +   0 + lane]);
      f16x8 v1 = __builtin_bit_cast(f16x8, KV[buf][512 + kstep * 256 +  64 + lane]);
      f16x8 v2 = __builtin_bit_cast(f16x8, KV[buf][512 + kstep * 256 + 128 + lane]);
      f16x8 v3 = __builtin_bit_cast(f16x8, KV[buf][512 + kstep * 256 + 192 + lane]);
      O0 = __builtin_amdgcn_mfma_f32_32x32x16_f16(pf, v0, O0, 0, 0, 0);
      O1 = __builtin_amdgcn_mfma_f32_32x32x16_f16(pf, v1, O1, 0, 0, 0);
      O2 = __builtin_amdgcn_mfma_f32_32x32x16_f16(pf, v2, O2, 0, 0, 0);
      O3 = __builtin_amdgcn_mfma_f32_32x32x16_f16(pf, v3, O3, 0, 0, 0);
    }
  }

  // ---- epilogue ----
  lsum += __shfl_xor(lsum, 32);           // combine the two key-halves

  if (PARTIAL) {
    if (lhalf == 0) ws_l[ks * S_LEN + qw + lrow] = lsum;   // plain store
    float* obase = (ks == 0) ? out
                 : (float*)(ws + PART_OFF) + (size_t)(ks - 1) * S_LEN * D_K;
    #pragma unroll
    for (int r = 0; r < 16; ++r) {
      int row = (r & 3) + 8 * (r >> 2) + 4 * lhalf;
      float* dst = obase + (size_t)(qw + row) * D_K + lrow;
      dst[ 0] = O0[r];
      dst[32] = O1[r];
      dst[64] = O2[r];
      dst[96] = O3[r];
    }
  } else {
    if (lhalf == 0) atomicAdd(ws_l + qw + lrow, lsum);
    #pragma unroll
    for (int r = 0; r < 16; ++r) {
      int row = (r & 3) + 8 * (r >> 2) + 4 * lhalf;
      float* dst = out + (size_t)(qw + row) * D_K + lrow;
      atomicAdd(dst +  0, O0[r]);
      atomicAdd(dst + 32, O1[r]);
      atomicAdd(dst + 64, O2[r]);
      atomicAdd(dst + 96, O3[r]);
    }
  }
}

// ---------------- reduce partials (nparts>0) or just normalize (nparts=0) ----
__global__ __launch_bounds__(256) void attn_norm(float* __restrict__ out,
                                                 const float* __restrict__ lpart,
                                                 const float* __restrict__ opart,
                                                 int nparts) {
  int i = blockIdx.x * 256 + threadIdx.x;  // float4 index, 262144 total
  int q = i >> 5;
  float4* o4 = (float4*)out;
  float4 acc = o4[i];
  float l = lpart[q];
  for (int s = 1; s <= nparts; ++s) {
    float4 p = ((const float4*)opart)[(size_t)(s - 1) * 262144 + i];
    acc.x += p.x; acc.y += p.y; acc.z += p.z; acc.w += p.w;
    l += lpart[s * S_LEN + q];
  }
  float inv = 1.0f / l;
  acc.x *= inv; acc.y *= inv; acc.z *= inv; acc.w *= inv;
  o4[i] = acc;
}

extern "C" void kernel_launch(void* const* d_in, const int* in_sizes, int n_in,
                              void* d_out, int out_size, void* d_ws, size_t ws_size,
                              hipStream_t stream) {
  const float* q = (const float*)d_in[0];
  const float* k = (const float*)d_in[1];
  const float* v = (const float*)d_in[2];
  float* out = (float*)d_out;
  char* ws = (char*)d_ws;
  const bool part = (ws_size >= WS_NEED);

  if (part) {
    attn_prep<false><<<dim3(512), dim3(512), 0, stream>>>(k, v, out, ws);
    attn_main<true><<<dim3(512), dim3(256), 0, stream>>>(q, out, ws);
    attn_norm<<<dim3(1024), dim3(256), 0, stream>>>(
        out, (const float*)(ws + WS_L_OFF), (const float*)(ws + PART_OFF), 7);
  } else {
    attn_prep<true><<<dim3(645), dim3(512), 0, stream>>>(k, v, out, ws);
    attn_main<false><<<dim3(512), dim3(256), 0, stream>>>(q, out, ws);
    attn_norm<<<dim3(1024), dim3(256), 0, stream>>>(
        out, (const float*)(ws + WS_L_OFF), (const float*)(ws + PART_OFF), 0);
  }
}